// Round 1
// baseline (311.802 us; speedup 1.0000x reference)
//
#include <hip/hip_runtime.h>
#include <stdint.h>

#define B_SZ 8192
#define N_F 12
#define H_DIM 512
#define K_DIM 1024
#define V_DIM 256

typedef __attribute__((ext_vector_type(8))) __bf16 bf16x8;
typedef __attribute__((ext_vector_type(4))) float f32x4;

// tanh-approx GELU in sigmoid form: x * sigmoid(2*sqrt(2/pi)*(x + 0.044715 x^3))
// max abs deviation from exact erf-GELU ~1e-3, well under the 4.6e-2 threshold.
// Sigmoid form avoids inf/inf NaN for large |x|.
__device__ inline float gelu_f(float x) {
  float t = 1.5957691216057308f * x * (1.0f + 0.044715f * x * x);
  return x / (1.0f + __expf(-t));
}

__device__ inline void gld_lds16(const void* g, void* l) {
  __builtin_amdgcn_global_load_lds(
      (const __attribute__((address_space(1))) void*)g,
      (__attribute__((address_space(3))) void*)l, 16, 0, 0);
}

// ---------------------------------------------------------------------------
// Kernel 1: per-row running cumsum + LN stats + second-half act (bf16)
// grid = B blocks, 256 threads. Thread t owns h = t and h = t+256.
// act2 layout: [N][B][H]  (n-major so each GEMM's A2 is a contiguous matrix)
// stats layout: [B][N][2] = (mu, rsigma)
// ---------------------------------------------------------------------------
__global__ __launch_bounds__(256) void k_prep(
    const float* __restrict__ ie, const int* __restrict__ feat,
    const float* __restrict__ tab, const float* __restrict__ gam,
    const float* __restrict__ bet, __bf16* __restrict__ act2,
    float* __restrict__ stats) {
  const int b = blockIdx.x;
  const int t = threadIdx.x;
  const int lane = t & 63, wid = t >> 6;
  __shared__ float redS[4], redQ[4], bc[2];

  const float* cb = ie + (size_t)b * H_DIM;
  const float c0 = cb[t], c1 = cb[t + 256];
  float s = c0 + c1, q = c0 * c0 + c1 * c1;
#pragma unroll
  for (int o = 32; o > 0; o >>= 1) {
    s += __shfl_down(s, o, 64);
    q += __shfl_down(q, o, 64);
  }
  if (lane == 0) { redS[wid] = s; redQ[wid] = q; }
  __syncthreads();
  if (t == 0) {
    bc[0] = redS[0] + redS[1] + redS[2] + redS[3];
    bc[1] = redQ[0] + redQ[1] + redQ[2] + redQ[3];
  }
  __syncthreads();
  const float S1 = bc[0], Q1 = bc[1];
  __syncthreads();

  const float g0 = gam[H_DIM + t], g1 = gam[H_DIM + t + 256];
  const float be0 = bet[H_DIM + t], be1 = bet[H_DIM + t + 256];

  float r0 = 0.f, r1 = 0.f;  // exclusive running sum, this thread's 2 lanes
  for (int n = 0; n < N_F; ++n) {
    s = r0 + r1;
    q = r0 * r0 + r1 * r1;
#pragma unroll
    for (int o = 32; o > 0; o >>= 1) {
      s += __shfl_down(s, o, 64);
      q += __shfl_down(q, o, 64);
    }
    if (lane == 0) { redS[wid] = s; redQ[wid] = q; }
    __syncthreads();
    if (t == 0) {
      bc[0] = redS[0] + redS[1] + redS[2] + redS[3];
      bc[1] = redQ[0] + redQ[1] + redQ[2] + redQ[3];
    }
    __syncthreads();
    const float mean = (S1 + bc[0]) * (1.0f / 1024.0f);
    const float var = (Q1 + bc[1]) * (1.0f / 1024.0f) - mean * mean;
    const float rs = rsqrtf(var + 1e-5f);
    if (t == 0) {
      float* sp = stats + ((size_t)b * N_F + n) * 2;
      sp[0] = mean;
      sp[1] = rs;
    }
    __syncthreads();  // protect redS/bc reuse next iteration
    const size_t ob = ((size_t)n * B_SZ + b) * H_DIM;
    act2[ob + t] = (__bf16)gelu_f((r0 - mean) * rs * g0 + be0);
    act2[ob + t + 256] = (__bf16)gelu_f((r1 - mean) * rs * g1 + be1);
    if (n < N_F - 1) {
      const int f = feat[b * N_F + n];
      const float* tr = tab + ((size_t)n * V_DIM + f) * H_DIM;
      r0 += tr[t];
      r1 += tr[t + 256];
    }
  }
}

// ---------------------------------------------------------------------------
// Kernel 2: pred_W [N][K][V] fp32  ->  Wt [N][V][K] bf16 (LDS-tiled transpose)
// grid = N * (K/32) * (V/32) = 12*32*8 = 3072 blocks, 256 threads (32x8)
// ---------------------------------------------------------------------------
__global__ __launch_bounds__(256) void k_wt(const float* __restrict__ W,
                                            __bf16* __restrict__ Wt) {
  __shared__ float tile[32][33];
  const int bid = blockIdx.x;
  const int n = bid >> 8;
  const int rem = bid & 255;
  const int kt = rem >> 3, vt = rem & 7;
  const int tx = threadIdx.x & 31, ty = threadIdx.x >> 5;
  const float* src = W + (size_t)n * K_DIM * V_DIM;
#pragma unroll
  for (int i = 0; i < 4; ++i) {
    const int k = kt * 32 + ty + i * 8;
    tile[ty + i * 8][tx] = src[(size_t)k * V_DIM + vt * 32 + tx];
  }
  __syncthreads();
  __bf16* dst = Wt + (size_t)n * V_DIM * K_DIM;
#pragma unroll
  for (int i = 0; i < 4; ++i) {
    const int v = vt * 32 + ty + i * 8;
    dst[(size_t)v * K_DIM + kt * 32 + tx] = (__bf16)tile[tx][ty + i * 8];
  }
}

// ---------------------------------------------------------------------------
// Kernel 3: fused A-gen + GEMM.  grid = (B/128, N), 512 threads (8 waves).
// Tile: BM=128 rows x BN=256 (=V) cols, BK=64. Wave grid 2x4, 64x64 per wave,
// acc[4][4] of 16x16x32 bf16 MFMA. K-iters 0..7: A computed from ctx via
// LN+GELU; K-iters 8..15: A = precomputed act2 via global_load_lds. W tiles
// always via global_load_lds (bf16, k-contiguous).
// ---------------------------------------------------------------------------
__global__ __launch_bounds__(512, 4) void k_gemm(
    const float* __restrict__ ie, const __bf16* __restrict__ act2,
    const __bf16* __restrict__ Wt, const float* __restrict__ stats,
    const float* __restrict__ gam, const float* __restrict__ bet,
    const float* __restrict__ bias, float* __restrict__ out) {
  constexpr int BM = 128, BN = 256, BK = 64;
  __shared__ __align__(16) __bf16 As[BM * BK];  // 16 KB, row-major [m][k]
  __shared__ __align__(16) __bf16 Ws[BN * BK];  // 32 KB, row-major [v][k]
  __shared__ float muL[BM], rsL[BM];

  const int n = blockIdx.y;
  const int b0 = blockIdx.x * BM;
  const int t = threadIdx.x;
  const int lane = t & 63;
  const int w = t >> 6;    // 0..7
  const int wm = w & 1;    // 0..1 (m slab)
  const int wn = w >> 1;   // 0..3 (n slab)
  const int l15 = lane & 15;
  const int lq = lane >> 4;

  if (t < 2 * BM) {
    const int r = t >> 1, which = t & 1;
    const float v = stats[((size_t)(b0 + r) * N_F + n) * 2 + which];
    if (which == 0) muL[r] = v; else rsL[r] = v;
  }

  f32x4 acc[4][4];
#pragma unroll
  for (int i = 0; i < 4; ++i)
#pragma unroll
    for (int j = 0; j < 4; ++j) acc[i][j] = (f32x4){0.f, 0.f, 0.f, 0.f};

  const __bf16* act2n = act2 + (size_t)n * B_SZ * H_DIM;
  const __bf16* Wtn = Wt + (size_t)n * V_DIM * K_DIM;

  const int o8 = t & 7;      // k-octet for A1 staging
  const int rA = t >> 3;     // 0..63 row for A1 staging
  const int lr8 = lane >> 3; // 0..7
  const int lo8 = lane & 7;

  for (int kt = 0; kt < 16; ++kt) {
    const int k0 = kt * BK;
    __syncthreads();  // prior compute done before LDS overwrite
    // --- stage W tile: wave w covers v rows [w*32, w*32+32) ---
#pragma unroll
    for (int p = 0; p < 4; ++p) {
      const int v0 = w * 32 + p * 8;
      gld_lds16(Wtn + (size_t)(v0 + lr8) * K_DIM + k0 + lo8 * 8, Ws + v0 * BK);
    }
    if (k0 < H_DIM) {
      // --- A from ctx: LN+GELU on the fly ---
      const int kk = k0 + o8 * 8;
      const float4 gg0 = *(const float4*)(gam + kk);
      const float4 gg1 = *(const float4*)(gam + kk + 4);
      const float4 bt0 = *(const float4*)(bet + kk);
      const float4 bt1 = *(const float4*)(bet + kk + 4);
#pragma unroll
      for (int half = 0; half < 2; ++half) {
        const int r = rA + half * 64;
        const float* cp = ie + (size_t)(b0 + r) * H_DIM + kk;
        const float4 x0 = *(const float4*)cp;
        const float4 x1 = *(const float4*)(cp + 4);
        const float mu = muL[r], rs = rsL[r];
        bf16x8 pk;
        pk[0] = (__bf16)gelu_f((x0.x - mu) * rs * gg0.x + bt0.x);
        pk[1] = (__bf16)gelu_f((x0.y - mu) * rs * gg0.y + bt0.y);
        pk[2] = (__bf16)gelu_f((x0.z - mu) * rs * gg0.z + bt0.z);
        pk[3] = (__bf16)gelu_f((x0.w - mu) * rs * gg0.w + bt0.w);
        pk[4] = (__bf16)gelu_f((x1.x - mu) * rs * gg1.x + bt1.x);
        pk[5] = (__bf16)gelu_f((x1.y - mu) * rs * gg1.y + bt1.y);
        pk[6] = (__bf16)gelu_f((x1.z - mu) * rs * gg1.z + bt1.z);
        pk[7] = (__bf16)gelu_f((x1.w - mu) * rs * gg1.w + bt1.w);
        *(bf16x8*)(As + r * BK + o8 * 8) = pk;
      }
    } else {
      // --- A from act2 (already LN+GELU'd, bf16): async copy ---
#pragma unroll
      for (int p = 0; p < 2; ++p) {
        const int r0 = w * 16 + p * 8;
        gld_lds16(act2n + (size_t)(b0 + r0 + lr8) * H_DIM + (k0 - H_DIM) + lo8 * 8,
                  As + r0 * BK);
      }
    }
    __syncthreads();  // emits s_waitcnt vmcnt(0) lgkmcnt(0) + barrier
    // --- 2 MFMA k-steps over the 64-wide chunk ---
#pragma unroll
    for (int ks = 0; ks < 2; ++ks) {
      const int koff = ks * 32 + lq * 8;
      bf16x8 af[4], bb[4];
#pragma unroll
      for (int i = 0; i < 4; ++i)
        af[i] = *(const bf16x8*)(As + (wm * 64 + i * 16 + l15) * BK + koff);
#pragma unroll
      for (int j = 0; j < 4; ++j)
        bb[j] = *(const bf16x8*)(Ws + (wn * 64 + j * 16 + l15) * BK + koff);
#pragma unroll
      for (int i = 0; i < 4; ++i)
#pragma unroll
        for (int j = 0; j < 4; ++j)
          acc[i][j] =
              __builtin_amdgcn_mfma_f32_16x16x32_bf16(af[i], bb[j], acc[i][j], 0, 0, 0);
    }
  }

  // epilogue: C/D layout col=lane&15, row=(lane>>4)*4+reg  [m89/m91 verified]
#pragma unroll
  for (int j = 0; j < 4; ++j) {
    const int v = wn * 64 + j * 16 + l15;
    const float bv = bias[n * V_DIM + v];
#pragma unroll
    for (int i = 0; i < 4; ++i) {
      const int rb = wm * 64 + i * 16 + lq * 4;
#pragma unroll
      for (int r = 0; r < 4; ++r) {
        out[((size_t)(b0 + rb + r) * N_F + n) * V_DIM + v] = acc[i][j][r] + bv;
      }
    }
  }
}

// ---------------------------------------------------------------------------
extern "C" void kernel_launch(void* const* d_in, const int* in_sizes, int n_in,
                              void* d_out, int out_size, void* d_ws, size_t ws_size,
                              hipStream_t stream) {
  const float* ie = (const float*)d_in[0];    // [B][H]
  const int* feat = (const int*)d_in[1];      // [B][N]
  const float* tab = (const float*)d_in[2];   // [N][V][H]
  const float* gam = (const float*)d_in[3];   // [2H]
  const float* bet = (const float*)d_in[4];   // [2H]
  const float* predW = (const float*)d_in[5]; // [N][2H][V]
  const float* predb = (const float*)d_in[6]; // [N][V]
  float* out = (float*)d_out;                 // [B][N][V]

  // ws layout (needs ~102.8 MB):
  //   act2  bf16 [N][B][H]   = 100,663,296 B
  //   stats fp32 [B][N][2]   =     786,432 B
  //   Wt    bf16 [N][V][K]   =   6,291,456 B
  char* ws = (char*)d_ws;
  __bf16* act2 = (__bf16*)ws;
  float* stats = (float*)(ws + 100663296);
  __bf16* Wt = (__bf16*)(ws + 100663296 + 786432);

  hipLaunchKernelGGL(k_prep, dim3(B_SZ), dim3(256), 0, stream, ie, feat, tab,
                     gam, bet, act2, stats);
  hipLaunchKernelGGL(k_wt, dim3(3072), dim3(256), 0, stream, predW, Wt);
  hipLaunchKernelGGL(k_gemm, dim3(B_SZ / 128, N_F), dim3(512), 0, stream, ie,
                     act2, Wt, stats, gam, bet, predb, out);
}

// Round 2
// 279.356 us; speedup vs baseline: 1.1161x; 1.1161x over previous
//
#include <hip/hip_runtime.h>
#include <stdint.h>

#define B_SZ 8192
#define N_F 12
#define H_DIM 512
#define K_DIM 1024
#define V_DIM 256

typedef __attribute__((ext_vector_type(8))) __bf16 bf16x8;
typedef __attribute__((ext_vector_type(4))) float f32x4;

// tanh-approx GELU in sigmoid form; |err| vs exact erf-GELU ~1e-3 << 4.6e-2.
__device__ inline float gelu_f(float x) {
  float t = 1.5957691216057308f * x * (1.0f + 0.044715f * x * x);
  return x / (1.0f + __expf(-t));
}

__device__ inline void gld_lds16(const void* g, void* l) {
  __builtin_amdgcn_global_load_lds(
      (const __attribute__((address_space(1))) void*)g,
      (__attribute__((address_space(3))) void*)l, 16, 0, 0);
}

// ---------------------------------------------------------------------------
// Kernel 1: wave-per-row. Lane l owns dims [l*8, l*8+8) of H=512.
// Running exclusive cumsum in registers; shuffle-only reductions (no LDS).
// act2 stored bf16 [N][B][H] with 16B-chunk XOR swizzle: chunk c of each
// 64-elem K-group stored at position c^(b&7) so that k_gemm's contiguous
// global_load_lds staging lands a bank-conflict-free layout in LDS.
// ---------------------------------------------------------------------------
__global__ __launch_bounds__(256, 8) void k_prep(
    const float* __restrict__ ie, const int* __restrict__ feat,
    const float* __restrict__ tab, const float* __restrict__ gam,
    const float* __restrict__ bet, __bf16* __restrict__ act2,
    float* __restrict__ stats) {
  const int lane = threadIdx.x & 63;
  const int b = blockIdx.x * 4 + (threadIdx.x >> 6);

  const float* cb = ie + (size_t)b * H_DIM + lane * 8;
  float4 c0 = *(const float4*)cb;
  float4 c1 = *(const float4*)(cb + 4);
  float s = c0.x + c0.y + c0.z + c0.w + c1.x + c1.y + c1.z + c1.w;
  float q = c0.x * c0.x + c0.y * c0.y + c0.z * c0.z + c0.w * c0.w +
            c1.x * c1.x + c1.y * c1.y + c1.z * c1.z + c1.w * c1.w;
#pragma unroll
  for (int o = 1; o < 64; o <<= 1) {
    s += __shfl_xor(s, o, 64);
    q += __shfl_xor(q, o, 64);
  }
  const float S1 = s, Q1 = q;

  const float4 g0 = *(const float4*)(gam + H_DIM + lane * 8);
  const float4 g1 = *(const float4*)(gam + H_DIM + lane * 8 + 4);
  const float4 e0 = *(const float4*)(bet + H_DIM + lane * 8);
  const float4 e1 = *(const float4*)(bet + H_DIM + lane * 8 + 4);

  float r[8];
#pragma unroll
  for (int i = 0; i < 8; ++i) r[i] = 0.f;

  // swizzled chunk slot for this lane's 16B store (chunk index == lane)
  const int sw = (lane & ~7) | ((lane & 7) ^ (b & 7));
  __bf16* arow = act2 + (size_t)b * H_DIM + sw * 8;

  for (int n = 0; n < N_F; ++n) {
    s = 0.f; q = 0.f;
#pragma unroll
    for (int i = 0; i < 8; ++i) { s += r[i]; q += r[i] * r[i]; }
#pragma unroll
    for (int o = 1; o < 64; o <<= 1) {
      s += __shfl_xor(s, o, 64);
      q += __shfl_xor(q, o, 64);
    }
    const float mean = (S1 + s) * (1.0f / 1024.0f);
    const float var = (Q1 + q) * (1.0f / 1024.0f) - mean * mean;
    const float rs = rsqrtf(var + 1e-5f);
    if (lane == 0)
      *(float2*)(stats + ((size_t)b * N_F + n) * 2) = make_float2(mean, rs);

    bf16x8 pk;
    pk[0] = (__bf16)gelu_f((r[0] - mean) * rs * g0.x + e0.x);
    pk[1] = (__bf16)gelu_f((r[1] - mean) * rs * g0.y + e0.y);
    pk[2] = (__bf16)gelu_f((r[2] - mean) * rs * g0.z + e0.z);
    pk[3] = (__bf16)gelu_f((r[3] - mean) * rs * g0.w + e0.w);
    pk[4] = (__bf16)gelu_f((r[4] - mean) * rs * g1.x + e1.x);
    pk[5] = (__bf16)gelu_f((r[5] - mean) * rs * g1.y + e1.y);
    pk[6] = (__bf16)gelu_f((r[6] - mean) * rs * g1.z + e1.z);
    pk[7] = (__bf16)gelu_f((r[7] - mean) * rs * g1.w + e1.w);
    *(bf16x8*)(arow + (size_t)n * B_SZ * H_DIM) = pk;

    if (n < N_F - 1) {
      const int f = feat[b * N_F + n];
      const float* tr = tab + ((size_t)n * V_DIM + f) * H_DIM + lane * 8;
      const float4 t0 = *(const float4*)tr;
      const float4 t1 = *(const float4*)(tr + 4);
      r[0] += t0.x; r[1] += t0.y; r[2] += t0.z; r[3] += t0.w;
      r[4] += t1.x; r[5] += t1.y; r[6] += t1.z; r[7] += t1.w;
    }
  }
}

// ---------------------------------------------------------------------------
// Kernel 2: pred_W [N][K][V] fp32 -> Wt [N][V][K] bf16, chunk-swizzled by v&7
// so that gld staging in k_gemm lands conflict-free in LDS.
// grid = 12*32*8 = 3072 blocks, 256 threads.
// ---------------------------------------------------------------------------
__global__ __launch_bounds__(256) void k_wt(const float* __restrict__ W,
                                            __bf16* __restrict__ Wt) {
  __shared__ float tile[32][33];
  const int bid = blockIdx.x;
  const int n = bid >> 8;
  const int rem = bid & 255;
  const int kt = rem >> 3, vt = rem & 7;
  const int tx = threadIdx.x & 31, ty = threadIdx.x >> 5;
  const float* src = W + (size_t)n * K_DIM * V_DIM;
#pragma unroll
  for (int i = 0; i < 4; ++i) {
    const int k = kt * 32 + ty + i * 8;
    tile[ty + i * 8][tx] = src[(size_t)k * V_DIM + vt * 32 + tx];
  }
  __syncthreads();
  __bf16* dst = Wt + (size_t)n * V_DIM * K_DIM;
  const int t = threadIdx.x;
  if (t < 128) {
    const int v_l = t >> 2, c_l = t & 3;
    const int v = vt * 32 + v_l;
    bf16x8 pk;
#pragma unroll
    for (int e = 0; e < 8; ++e) pk[e] = (__bf16)tile[c_l * 8 + e][v_l];
    const int gc = kt * 4 + c_l;                       // global 16B-chunk idx
    const int swc = (gc & ~7) | ((gc & 7) ^ (v & 7));  // swizzled slot
    *(bf16x8*)(dst + (size_t)v * K_DIM + swc * 8) = pk;
  }
}

// ---------------------------------------------------------------------------
// Kernel 3: fused A-gen + GEMM. grid = (B/128, N), 512 threads (8 waves).
// BM=128 x BN=256(=V), BK=64. Wave grid 2x4, 64x64/wave, acc[4][4] of
// 16x16x32 bf16 MFMA. LDS layout XOR-swizzled (chunk c at slot c^(row&7));
// staged operands are pre-swizzled in global, so gld stays contiguous.
// ---------------------------------------------------------------------------
__global__ __launch_bounds__(512, 4) void k_gemm(
    const float* __restrict__ ie, const __bf16* __restrict__ act2,
    const __bf16* __restrict__ Wt, const float* __restrict__ stats,
    const float* __restrict__ gam, const float* __restrict__ bet,
    const float* __restrict__ bias, float* __restrict__ out) {
  constexpr int BM = 128, BN = 256, BK = 64;
  __shared__ __align__(16) __bf16 As[BM * BK];  // 16 KB
  __shared__ __align__(16) __bf16 Ws[BN * BK];  // 32 KB
  __shared__ float muL[BM], rsL[BM];

  const int n = blockIdx.y;
  const int b0 = blockIdx.x * BM;
  const int t = threadIdx.x;
  const int lane = t & 63;
  const int w = t >> 6;
  const int wm = w & 1;
  const int wn = w >> 1;
  const int l15 = lane & 15;
  const int lq = lane >> 4;

  if (t < 2 * BM) {
    const int r = t >> 1, which = t & 1;
    const float v = stats[((size_t)(b0 + r) * N_F + n) * 2 + which];
    if (which == 0) muL[r] = v; else rsL[r] = v;
  }

  f32x4 acc[4][4];
#pragma unroll
  for (int i = 0; i < 4; ++i)
#pragma unroll
    for (int j = 0; j < 4; ++j) acc[i][j] = (f32x4){0.f, 0.f, 0.f, 0.f};

  const __bf16* act2n = act2 + (size_t)n * B_SZ * H_DIM;
  const __bf16* Wtn = Wt + (size_t)n * V_DIM * K_DIM;

  const int o8 = t & 7;       // k-chunk for ctx A staging
  const int rA = t >> 3;      // 0..63 row
  const int lr8 = lane >> 3;  // 0..7
  const int lo8 = lane & 7;

  for (int kt = 0; kt < 16; ++kt) {
    const int k0 = kt * BK;
    __syncthreads();
    // --- stage W tile (pre-swizzled global -> contiguous gld) ---
#pragma unroll
    for (int p = 0; p < 4; ++p) {
      const int v0 = w * 32 + p * 8;
      gld_lds16(Wtn + (size_t)(v0 + lr8) * K_DIM + k0 + lo8 * 8, Ws + v0 * BK);
    }
    if (k0 < H_DIM) {
      // --- A from ctx: LN+GELU on the fly, swizzled ds_write ---
      const int kk = k0 + o8 * 8;
      const float4 gg0 = *(const float4*)(gam + kk);
      const float4 gg1 = *(const float4*)(gam + kk + 4);
      const float4 bt0 = *(const float4*)(bet + kk);
      const float4 bt1 = *(const float4*)(bet + kk + 4);
      const int swo = (o8 ^ (rA & 7)) * 8;  // (r&7)==(rA&7) for both halves
#pragma unroll
      for (int half = 0; half < 2; ++half) {
        const int r = rA + half * 64;
        const float* cp = ie + (size_t)(b0 + r) * H_DIM + kk;
        const float4 x0 = *(const float4*)cp;
        const float4 x1 = *(const float4*)(cp + 4);
        const float mu = muL[r], rs = rsL[r];
        bf16x8 pk;
        pk[0] = (__bf16)gelu_f((x0.x - mu) * rs * gg0.x + bt0.x);
        pk[1] = (__bf16)gelu_f((x0.y - mu) * rs * gg0.y + bt0.y);
        pk[2] = (__bf16)gelu_f((x0.z - mu) * rs * gg0.z + bt0.z);
        pk[3] = (__bf16)gelu_f((x0.w - mu) * rs * gg0.w + bt0.w);
        pk[4] = (__bf16)gelu_f((x1.x - mu) * rs * gg1.x + bt1.x);
        pk[5] = (__bf16)gelu_f((x1.y - mu) * rs * gg1.y + bt1.y);
        pk[6] = (__bf16)gelu_f((x1.z - mu) * rs * gg1.z + bt1.z);
        pk[7] = (__bf16)gelu_f((x1.w - mu) * rs * gg1.w + bt1.w);
        *(bf16x8*)(As + r * BK + swo) = pk;
      }
    } else {
      // --- A from act2 (pre-swizzled bf16): async copy ---
#pragma unroll
      for (int p = 0; p < 2; ++p) {
        const int r0 = w * 16 + p * 8;
        gld_lds16(act2n + (size_t)(b0 + r0 + lr8) * H_DIM + (k0 - H_DIM) + lo8 * 8,
                  As + r0 * BK);
      }
    }
    __syncthreads();
    // --- 2 MFMA k-steps, swizzled fragment reads (2-way max conflicts) ---
#pragma unroll
    for (int ks = 0; ks < 2; ++ks) {
      const int cs = ks * 4 + lq;  // 16B-chunk index within BK group
      bf16x8 af[4], bb[4];
#pragma unroll
      for (int i = 0; i < 4; ++i) {
        const int row = wm * 64 + i * 16 + l15;
        af[i] = *(const bf16x8*)(As + row * BK + ((cs ^ (row & 7)) << 3));
      }
#pragma unroll
      for (int j = 0; j < 4; ++j) {
        const int row = wn * 64 + j * 16 + l15;
        bb[j] = *(const bf16x8*)(Ws + row * BK + ((cs ^ (row & 7)) << 3));
      }
#pragma unroll
      for (int i = 0; i < 4; ++i)
#pragma unroll
        for (int j = 0; j < 4; ++j)
          acc[i][j] =
              __builtin_amdgcn_mfma_f32_16x16x32_bf16(af[i], bb[j], acc[i][j], 0, 0, 0);
    }
  }

  // epilogue: C/D layout col=lane&15, row=(lane>>4)*4+reg
#pragma unroll
  for (int j = 0; j < 4; ++j) {
    const int v = wn * 64 + j * 16 + l15;
    const float bv = bias[n * V_DIM + v];
#pragma unroll
    for (int i = 0; i < 4; ++i) {
      const int rb = wm * 64 + i * 16 + lq * 4;
#pragma unroll
      for (int r = 0; r < 4; ++r) {
        out[((size_t)(b0 + rb + r) * N_F + n) * V_DIM + v] = acc[i][j][r] + bv;
      }
    }
  }
}

// ---------------------------------------------------------------------------
extern "C" void kernel_launch(void* const* d_in, const int* in_sizes, int n_in,
                              void* d_out, int out_size, void* d_ws, size_t ws_size,
                              hipStream_t stream) {
  const float* ie = (const float*)d_in[0];
  const int* feat = (const int*)d_in[1];
  const float* tab = (const float*)d_in[2];
  const float* gam = (const float*)d_in[3];
  const float* bet = (const float*)d_in[4];
  const float* predW = (const float*)d_in[5];
  const float* predb = (const float*)d_in[6];
  float* out = (float*)d_out;

  char* ws = (char*)d_ws;
  __bf16* act2 = (__bf16*)ws;                        // 100,663,296 B
  float* stats = (float*)(ws + 100663296);           //     786,432 B
  __bf16* Wt = (__bf16*)(ws + 100663296 + 786432);   //   6,291,456 B

  hipLaunchKernelGGL(k_prep, dim3(B_SZ / 4), dim3(256), 0, stream, ie, feat,
                     tab, gam, bet, act2, stats);
  hipLaunchKernelGGL(k_wt, dim3(3072), dim3(256), 0, stream, predW, Wt);
  hipLaunchKernelGGL(k_gemm, dim3(B_SZ / 128, N_F), dim3(512), 0, stream, ie,
                     act2, Wt, stats, gam, bet, predb, out);
}